// Round 6
// baseline (7399.059 us; speedup 1.0000x reference)
//
#include <hip/hip_runtime.h>
#include <hip/hip_bf16.h>
#include <stdint.h>

// Problem dims
#define T_  48
#define B_  16
#define HW_ 768
#define D_  684
#define N_  256
#define A_  512

// Workspace layout (float offsets). Footprint identical to R3/R5 (proven).
#define OFF_SZ     0u
#define OFF_SR     196608u
#define OFF_SH     393216u
#define OFF_UHZT   589824u    // gates1 weights [k][n] x3
#define OFF_UHZ2T  786432u    // gates2 h-weights [k][n] x3
// 983040..1179648: prep scratch for Wy transposes (consumed by embproj), then:
#define OFF_G2H    983040u    // Uh2.h1 [b][3][256] = 12288 (written by step0/alpha tail)
#define OFF_CTR    995328u    // 16 uints (arrival counters per b)
#define OFF_WAH    1114112u   // Wa.h1 + Ua_b + Uf_b  [b][512] = 8192
#define OFF_WAT    1179648u   // [k=256][a=512]
#define OFF_WCZT   1310720u   // [d=684][n=256] x3
#define OFF_UAB    1836032u   // Ua bf16 [a=512][k=688] = 176128 floats (ends 2012160)
#define OFF_KCB    2186240u   // K_comb^T bf16 [a=512][k=128] = 32768 floats
#define OFF_G2CT   2219008u   // Wc.ct accum [b][3][256] = 12288 (atomic)
#define OFF_H1     2251776u   // h1 state B*N
#define OFF_AP     2275008u   // alpha_past B*HW
#define OFF_AUN    2287296u   // per-step e partial sums (atomic) B*HW
#define OFF_UACTX  2299584u   // Ua_ctx bf16 [b][hw][a]; end 5445312

// d_out offsets
#define OUT_H2 0u
#define OUT_CT 196608u
#define OUT_AL 721920u
#define OUT_AP 1311744u

typedef __attribute__((ext_vector_type(8))) short bf16x8;
typedef __attribute__((ext_vector_type(16))) float floatx16;

__device__ __forceinline__ float sigf(float x)  { return 1.f / (1.f + __expf(-x)); }
__device__ __forceinline__ float tanhf_(float x){ float e = __expf(2.f*x); return 1.f - 2.f/(e + 1.f); }
__device__ __forceinline__ float bfval(unsigned short u){ return __uint_as_float(((unsigned)u) << 16); }
__device__ __forceinline__ unsigned short f2bf(float f){
  unsigned int x = __float_as_uint(f);
  return (unsigned short)((x + 0x7fffu + ((x >> 16) & 1u)) >> 16);  // RNE
}

// ---------------- prep: weight transposes + Ua->bf16 + zero alpha_past ----------------
__global__ void k_prep(const float* __restrict__ Uhz, const float* __restrict__ Uhr, const float* __restrict__ Uhh,
                       const float* __restrict__ Uhz2, const float* __restrict__ Uhr2, const float* __restrict__ Uhh2,
                       const float* __restrict__ Wyz, const float* __restrict__ Wyr, const float* __restrict__ Wyh,
                       const float* __restrict__ Wa, const float* __restrict__ Wcz, const float* __restrict__ Wcr,
                       const float* __restrict__ Wch, const float* __restrict__ Ua, float* __restrict__ ws)
{
  int i = blockIdx.x * 256 + threadIdx.x;
  if (i < 589824) {                     // 9 x (256x256) -> [k][n]
    int m = i >> 16, rem = i & 65535, r = rem >> 8, c = rem & 255;
    const float* s;
    unsigned dst;
    switch (m) { case 0: s=Uhz;  dst=OFF_UHZT;           break;
                 case 1: s=Uhr;  dst=OFF_UHZT+65536u;    break;
                 case 2: s=Uhh;  dst=OFF_UHZT+131072u;   break;
                 case 3: s=Uhz2; dst=OFF_UHZ2T;          break;
                 case 4: s=Uhr2; dst=OFF_UHZ2T+65536u;   break;
                 case 5: s=Uhh2; dst=OFF_UHZ2T+131072u;  break;
                 case 6: s=Wyz;  dst=983040u;            break;  // scratch (embproj)
                 case 7: s=Wyr;  dst=1048576u;           break;
                 default: s=Wyh; dst=1114112u;           break;}
    ws[dst + c*256 + r] = s[rem];
  } else if (i < 720896) {              // Wa [512][256] -> WaT [256][512]
    int j = i - 589824, r = j >> 8, c = j & 255;
    ws[OFF_WAT + c*512 + r] = Wa[j];
  } else if (i < 1246208) {             // Wc* [256][684] -> [684][256]
    int j = i - 720896; int m = j / 175104; int rem = j - m*175104;
    int r = rem / 684, c = rem - r*684;
    const float* s = (m == 0) ? Wcz : (m == 1) ? Wcr : Wch;
    ws[OFF_WCZT + m*175104 + c*256 + r] = s[rem];
  } else if (i < 1596416) {             // Ua [512][684] fp32 -> bf16 [a][688]
    int j = i - 1246208; int a = j / 684, d = j - a*684;
    unsigned short* uab = (unsigned short*)(ws + OFF_UAB);
    uab[(size_t)a*688 + d] = f2bf(Ua[j]);
  } else if (i < 1598464) {             // UaB k-padding zeros
    int j = i - 1596416; int a = j >> 2, d = 684 + (j & 3);
    unsigned short* uab = (unsigned short*)(ws + OFF_UAB);
    uab[(size_t)a*688 + d] = 0;
  } else if (i < 1610752) {             // zero alpha_past
    ws[OFF_AP + (i - 1598464)] = 0.f;
  }
}

// ---------------- K_comb bf16 [a=512][k=128]: one block per conv tap k ----------------
__global__ void __launch_bounds__(256) k_kcomb(const float* __restrict__ Uf, const float* __restrict__ Qw,
                                               float* __restrict__ ws)
{
  unsigned short* kcb = (unsigned short*)(ws + OFF_KCB);
  int tid = threadIdx.x, k = blockIdx.x;
  if (k >= 121) {                       // zero-pad columns 121..127
    for (int a = tid; a < 512; a += 256) kcb[(size_t)a*128 + k] = 0;
    return;
  }
  __shared__ float sQ[512];
  for (int c = tid; c < 512; c += 256) sQ[c] = Qw[c*121 + k];
  __syncthreads();
  int rl = tid >> 5, cl = tid & 31;
  for (int r0 = 0; r0 < 512; r0 += 8) {
    int a = r0 + rl;
    float acc = 0.f;
    #pragma unroll 4
    for (int c = cl; c < 512; c += 32) acc += Uf[(size_t)a*512 + c] * sQ[c];
    acc += __shfl_xor(acc, 1); acc += __shfl_xor(acc, 2); acc += __shfl_xor(acc, 4);
    acc += __shfl_xor(acc, 8); acc += __shfl_xor(acc, 16);
    if (cl == 0) kcb[(size_t)a*128 + k] = f2bf(acc);
  }
}

// ---------------- embedding projections (Wy* transposes from scratch) ----------------
__global__ void k_embproj(const float* __restrict__ emb, const float* __restrict__ bz,
                          const float* __restrict__ br, const float* __restrict__ bh,
                          float* __restrict__ ws)
{
  __shared__ __align__(16) float s_e[256 * 16];
  int tid = threadIdx.x, row0 = blockIdx.x * 16;
  for (int i = tid; i < 4096; i += 256) { int r = i >> 8, m = i & 255; s_e[m*16 + r] = emb[(row0 + r)*256 + m]; }
  __syncthreads();
  int n = tid;
  float az[16], arr[16], ahh[16];
  float vz = bz[n], vr = br[n], vh = bh[n];
  #pragma unroll
  for (int r = 0; r < 16; ++r) { az[r] = vz; arr[r] = vr; ahh[r] = vh; }
  for (int m = 0; m < 256; ++m) {
    float wz = ws[983040u + m*256 + n];
    float wr = ws[1048576u + m*256 + n];
    float wh = ws[1114112u + m*256 + n];
    #pragma unroll
    for (int r = 0; r < 16; ++r) { float e = s_e[m*16 + r]; az[r] += wz*e; arr[r] += wr*e; ahh[r] += wh*e; }
  }
  #pragma unroll
  for (int r = 0; r < 16; ++r) {
    int ro = (row0 + r)*256 + n;
    ws[OFF_SZ + ro] = az[r]; ws[OFF_SR + ro] = arr[r]; ws[OFF_SH + ro] = ahh[r];
  }
}

// ---------------- Ua_ctx via bf16 MFMA: grid 192 = b(16) x hw-chunk(12 of 64) ----------------
__global__ void __launch_bounds__(256) k_uactx(const float* __restrict__ ctx, float* __restrict__ ws)
{
  __shared__ unsigned short sA[64 * 24];     // [m=hw][k=16], stride 24 (16B-aligned rows)
  int tid = threadIdx.x;
  int b = blockIdx.x / 12, ch = blockIdx.x % 12, hw0 = ch * 64;
  const unsigned short* uab = (const unsigned short*)(ws + OFF_UAB);
  int lane = tid & 63, w = tid >> 6, mw = w >> 1, nw = w & 1;
  int c5 = lane & 31, q = lane >> 5;
  int m = mw*32 + c5;
  int nb = nw*256;
  floatx16 acc[8];
  #pragma unroll
  for (int nt = 0; nt < 8; ++nt)
    #pragma unroll
    for (int r = 0; r < 16; ++r) acc[nt][r] = 0.f;
  int dd = tid >> 4, iw = tid & 15;
  for (int kt = 0; kt < 43; ++kt) {
    int d = kt*16 + dd;
    float4 v = {0.f, 0.f, 0.f, 0.f};
    if (d < 684) v = *(const float4*)(ctx + ((size_t)(b*684 + d))*768 + hw0 + iw*4);
    __syncthreads();
    sA[(iw*4 + 0)*24 + dd] = f2bf(v.x);
    sA[(iw*4 + 1)*24 + dd] = f2bf(v.y);
    sA[(iw*4 + 2)*24 + dd] = f2bf(v.z);
    sA[(iw*4 + 3)*24 + dd] = f2bf(v.w);
    __syncthreads();
    bf16x8 af = *(const bf16x8*)(sA + m*24 + q*8);
    #pragma unroll
    for (int nt = 0; nt < 8; ++nt) {
      bf16x8 bf = *(const bf16x8*)(uab + (size_t)(nb + nt*32 + c5)*688 + kt*16 + q*8);
      acc[nt] = __builtin_amdgcn_mfma_f32_32x32x16_bf16(af, bf, acc[nt], 0, 0, 0);
    }
  }
  unsigned short* up = (unsigned short*)(ws + OFF_UACTX);
  #pragma unroll
  for (int nt = 0; nt < 8; ++nt) {
    int col = nb + nt*32 + c5;
    #pragma unroll
    for (int r = 0; r < 16; ++r) {
      int row32 = (r & 3) + 8*(r >> 2) + 4*q;
      int hw = hw0 + mw*32 + row32;
      up[((size_t)(b*768 + hw))*512 + col] = f2bf(acc[nt][r]);
    }
  }
}

// ---------------- step0: h1(0), WaH(0), G2H(0), zero AUN/G2CT/ctr ----------------
__global__ void __launch_bounds__(256) k_step0(const float* __restrict__ inits, const float* __restrict__ maskp,
                                               const float* __restrict__ Uab, const float* __restrict__ Ufb,
                                               float* __restrict__ ws)
{
  __shared__ float s_h[256], s_h1[256];
  int b = blockIdx.x, n = threadIdx.x;
  s_h[n] = inits[b*256 + n];
  __syncthreads();
  {
    float z = ws[OFF_SZ + (0*16 + b)*256 + n], r = ws[OFF_SR + (0*16 + b)*256 + n];
    float sh = ws[OFF_SH + (0*16 + b)*256 + n], uh = 0.f;
    #pragma unroll 4
    for (int k = 0; k < 256; ++k) {
      float hk = s_h[k];
      z  += ws[OFF_UHZT + k*256 + n] * hk;
      r  += ws[OFF_UHZT + 65536u + k*256 + n] * hk;
      uh += ws[OFF_UHZT + 131072u + k*256 + n] * hk;
    }
    float z1 = sigf(z), r1 = sigf(r);
    float h1p = tanhf_(uh * r1 + sh);
    float m = maskp[0*16 + b];
    float h = s_h[n];
    float h1 = m*(z1*h + (1.f - z1)*h1p) + (1.f - m)*h;
    s_h1[n] = h1;
    ws[OFF_H1 + b*256 + n] = h1;
  }
  __syncthreads();
  #pragma unroll
  for (int half = 0; half < 2; ++half) {
    int a = n + half*256;
    float acc = 0.f;
    #pragma unroll 4
    for (int k = 0; k < 256; ++k) acc += ws[OFF_WAT + k*512 + a] * s_h1[k];
    ws[OFF_WAH + b*512 + a] = acc + Uab[a] + Ufb[a];
  }
  #pragma unroll
  for (int g = 0; g < 3; ++g) {
    float acc = 0.f;
    #pragma unroll 4
    for (int k = 0; k < 256; ++k) acc += ws[OFF_UHZ2T + g*65536u + k*256 + n] * s_h1[k];
    ws[OFF_G2H + (b*3 + g)*256 + n] = acc;
  }
  for (int i = n; i < 768; i += 256) ws[OFF_AUN + b*768 + i] = 0.f;
  for (int i = n; i < 768; i += 256) ws[OFF_G2CT + b*768 + i] = 0.f;
  if (n == 0) ((unsigned*)(ws + OFF_CTR))[b] = 0u;
}

// ---------------- cover: bf16 MFMA GEMM + tanh + va partial e ----------------
// grid 384 = b(16) x mt(12) x nt2(2); block 256 = 4 waves
__global__ void __launch_bounds__(256) k_cover(const float* __restrict__ va, float* __restrict__ ws)
{
  __shared__ unsigned short sA[64 * 136];
  __shared__ float sWah[512];
  __shared__ float sVa[512];
  int tid = threadIdx.x;
  int blk = blockIdx.x;
  int b = blk / 24; int chA = blk % 24; int mt = chA >> 1; int nt2 = chA & 1;
  for (int i = tid; i < 512; i += 256) { sWah[i] = ws[OFF_WAH + b*512 + i]; sVa[i] = va[i]; }
  const float* ap = ws + OFF_AP + b*768;
  for (int idx = tid; idx < 64*128; idx += 256) {
    int r = idx & 63, k = idx >> 6;
    int hw = mt*64 + r; int hh = hw / 48; int wwp = hw - hh*48;
    float v = 0.f;
    if (k < 121) {
      int kh = k / 11, kw = k - kh*11;
      int shh = hh + kh - 5, sww = wwp + kw - 5;
      if (shh >= 0 && shh < 16 && sww >= 0 && sww < 48) v = ap[shh*48 + sww];
    }
    sA[r*136 + k] = f2bf(v);
  }
  __syncthreads();
  int lane = tid & 63; int w = tid >> 6; int mw = w >> 1; int nw = w & 1;
  int c5 = lane & 31; int q = lane >> 5;
  bf16x8 af[8];
  {
    int m = mw*32 + c5;
    #pragma unroll
    for (int ks = 0; ks < 8; ++ks)
      af[ks] = *(const bf16x8*)(sA + m*136 + ks*16 + q*8);
  }
  const unsigned short* kct = (const unsigned short*)(ws + OFF_KCB);
  const unsigned short* uact = (const unsigned short*)(ws + OFF_UACTX);
  float e_part[16];
  #pragma unroll
  for (int r = 0; r < 16; ++r) e_part[r] = 0.f;

  for (int sp = 0; sp < 2; ++sp) {
    int n_base = nt2*256 + nw*128 + sp*64;
    floatx16 acc[2];
    #pragma unroll
    for (int r = 0; r < 16; ++r) { acc[0][r] = 0.f; acc[1][r] = 0.f; }
    const bf16x8* kb0 = (const bf16x8*)(kct + (size_t)(n_base + c5)*128 + q*8);
    const bf16x8* kb1 = (const bf16x8*)(kct + (size_t)(n_base + 32 + c5)*128 + q*8);
    #pragma unroll
    for (int ks = 0; ks < 8; ++ks) {
      bf16x8 b0 = kb0[ks*2];
      bf16x8 b1 = kb1[ks*2];
      acc[0] = __builtin_amdgcn_mfma_f32_32x32x16_bf16(af[ks], b0, acc[0], 0, 0, 0);
      acc[1] = __builtin_amdgcn_mfma_f32_32x32x16_bf16(af[ks], b1, acc[1], 0, 0, 0);
    }
    #pragma unroll
    for (int half = 0; half < 2; ++half) {
      int col = n_base + half*32 + c5;
      float vav = sVa[col], wah = sWah[col];
      #pragma unroll
      for (int r = 0; r < 16; ++r) {
        int row32 = (r & 3) + 8*(r >> 2) + 4*q;
        int hw = mt*64 + mw*32 + row32;
        float x = acc[half][r] + wah + bfval(uact[((size_t)(b*768 + hw))*512 + col]);
        e_part[r] += vav * tanhf_(x);
      }
    }
  }
  #pragma unroll
  for (int r = 0; r < 16; ++r) {
    float v = e_part[r];
    v += __shfl_xor(v, 1); v += __shfl_xor(v, 2); v += __shfl_xor(v, 4);
    v += __shfl_xor(v, 8); v += __shfl_xor(v, 16);
    e_part[r] = v;
  }
  if (c5 == 0) {
    #pragma unroll
    for (int r = 0; r < 16; ++r) {
      int row32 = (r & 3) + 8*(r >> 2) + 4*q;
      int hw = mt*64 + mw*32 + row32;
      atomicAdd(&ws[OFF_AUN + b*768 + hw], e_part[r]);
    }
  }
}

// ---------------- alpha: softmax+AP+ct+Wc.ct partials; LAST block per b does next-step GRU work ----------------
// grid 352 = b(16) x dc(22); dc owns d-rows [dc*32, dc*32+32)
__global__ void __launch_bounds__(256) k_alpha(int t, const float* __restrict__ ctx, const float* __restrict__ cmask,
                                               const float* __restrict__ vab, const float* __restrict__ maskp,
                                               const float* __restrict__ Uab, const float* __restrict__ Ufb,
                                               const float* __restrict__ bz2, const float* __restrict__ br2,
                                               const float* __restrict__ bh2,
                                               float* __restrict__ out, float* __restrict__ ws)
{
  __shared__ __align__(16) float s_al[768];
  __shared__ float s_red[4];
  __shared__ float s_ct[32];
  __shared__ int s_last;
  int tid = threadIdx.x;
  int b = blockIdx.x / 22, dc = blockIdx.x % 22;
  float vb = vab[0];
  float local = 0.f;
  for (int i = tid; i < 768; i += 256) {
    float e = ws[OFF_AUN + b*768 + i] + vb;
    float un = __expf(e) * cmask[b*768 + i];
    s_al[i] = un; local += un;
  }
  local += __shfl_xor(local, 1); local += __shfl_xor(local, 2); local += __shfl_xor(local, 4);
  local += __shfl_xor(local, 8); local += __shfl_xor(local, 16); local += __shfl_xor(local, 32);
  if ((tid & 63) == 0) s_red[tid >> 6] = local;
  __syncthreads();
  float inv = 1.f / (s_red[0] + s_red[1] + s_red[2] + s_red[3]);
  if (dc == 0) {
    float* outA = out + OUT_AL + (size_t)(t*16 + b)*768;
    float* outP = out + OUT_AP + (size_t)(t*16 + b)*768;
    for (int i = tid; i < 768; i += 256) {
      float av = s_al[i] * inv;
      float np = ws[OFF_AP + b*768 + i] + av;
      ws[OFF_AP + b*768 + i] = np;
      outA[i] = av; outP[i] = np;
    }
  }
  // ct for 32 d-rows (8 lanes per row)
  {
    int dl = tid >> 3, qq = tid & 7;
    int d = dc*32 + dl;
    if (d < 684) {
      const float4* cp  = (const float4*)(ctx + ((size_t)(b*684 + d))*768);
      const float4* alp = (const float4*)s_al;
      float s = 0.f;
      #pragma unroll 8
      for (int i = 0; i < 24; ++i) {
        float4 cv = cp[i*8 + qq]; float4 av = alp[i*8 + qq];
        s += cv.x*av.x + cv.y*av.y + cv.z*av.z + cv.w*av.w;
      }
      s += __shfl_xor(s, 1); s += __shfl_xor(s, 2); s += __shfl_xor(s, 4);
      s *= inv;
      if (qq == 0) {
        out[OUT_CT + (size_t)(t*16 + b)*684 + d] = s;
        s_ct[dl] = s;
      }
    } else if (qq == 0) {
      s_ct[dl] = 0.f;
    }
  }
  __syncthreads();
  // Wc . ct partials -> atomic accumulate into G2CT
  {
    int d0 = dc*32;
    int jm = 684 - d0; if (jm > 32) jm = 32;
    #pragma unroll
    for (int g = 0; g < 3; ++g) {
      const float* Wb = ws + OFF_WCZT + g*175104u;
      float acc = 0.f;
      for (int j = 0; j < jm; ++j) acc += Wb[(d0 + j)*256 + tid] * s_ct[j];
      atomicAdd(&ws[OFF_G2CT + (size_t)(b*3 + g)*256 + tid], acc);
    }
  }
  // arrival counter: barrier drains this block's atomics (vmcnt(0) before s_barrier)
  __syncthreads();
  if (tid == 0) {
    unsigned* ctr = (unsigned*)(ws + OFF_CTR);
    unsigned c = __hip_atomic_fetch_add(&ctr[b], 1u, __ATOMIC_ACQ_REL, __HIP_MEMORY_SCOPE_AGENT);
    s_last = (c == (unsigned)(22*t + 21)) ? 1 : 0;
  }
  __syncthreads();
  if (!s_last) return;
  // ---- tail (one block per b): h2 combine -> out; next-step gates1/h1/WaH/G2H ----
  float* s_h  = s_al;          // reuse LDS
  float* s_h1 = s_al + 256;
  int n = tid;
  float* g2ct = ws + OFF_G2CT;
  {
    float h1v = ws[OFF_H1 + b*256 + n];
    float gz = __hip_atomic_load(&g2ct[(b*3 + 0)*256 + n], __ATOMIC_RELAXED, __HIP_MEMORY_SCOPE_AGENT);
    float gr = __hip_atomic_load(&g2ct[(b*3 + 1)*256 + n], __ATOMIC_RELAXED, __HIP_MEMORY_SCOPE_AGENT);
    float gc = __hip_atomic_load(&g2ct[(b*3 + 2)*256 + n], __ATOMIC_RELAXED, __HIP_MEMORY_SCOPE_AGENT);
    gz += ws[OFF_G2H + (b*3 + 0)*256 + n];
    gr += ws[OFF_G2H + (b*3 + 1)*256 + n];
    float gu = ws[OFF_G2H + (b*3 + 2)*256 + n];
    float z2 = sigf(gz + bz2[n]);
    float r2 = sigf(gr + br2[n]);
    float h2p = tanhf_(gc + (gu + bh2[n]) * r2);
    float h2 = z2*h1v + (1.f - z2)*h2p;
    float m = maskp[t*16 + b];
    float hv = m*h2 + (1.f - m)*h1v;
    out[OUT_H2 + (size_t)(t*16 + b)*256 + n] = hv;
    s_h[n] = hv;
  }
  if (t >= 47) return;
  __syncthreads();
  {
    int ro = ((t+1)*16 + b)*256 + n;
    float z = ws[OFF_SZ + ro], r = ws[OFF_SR + ro], sh = ws[OFF_SH + ro], uh = 0.f;
    #pragma unroll 4
    for (int k = 0; k < 256; ++k) {
      float hk = s_h[k];
      z  += ws[OFF_UHZT + k*256 + n] * hk;
      r  += ws[OFF_UHZT + 65536u + k*256 + n] * hk;
      uh += ws[OFF_UHZT + 131072u + k*256 + n] * hk;
    }
    float z1 = sigf(z), r1 = sigf(r);
    float h1p = tanhf_(uh * r1 + sh);
    float m = maskp[(t+1)*16 + b];
    float h = s_h[n];
    float h1 = m*(z1*h + (1.f - z1)*h1p) + (1.f - m)*h;
    s_h1[n] = h1;
    ws[OFF_H1 + b*256 + n] = h1;
  }
  __syncthreads();
  #pragma unroll
  for (int half = 0; half < 2; ++half) {
    int a = n + half*256;
    float acc = 0.f;
    #pragma unroll 4
    for (int k = 0; k < 256; ++k) acc += ws[OFF_WAT + k*512 + a] * s_h1[k];
    ws[OFF_WAH + b*512 + a] = acc + Uab[a] + Ufb[a];
  }
  #pragma unroll
  for (int g = 0; g < 3; ++g) {
    float acc = 0.f;
    #pragma unroll 4
    for (int k = 0; k < 256; ++k) acc += ws[OFF_UHZ2T + g*65536u + k*256 + n] * s_h1[k];
    ws[OFF_G2H + (b*3 + g)*256 + n] = acc;
  }
  for (int i = n; i < 768; i += 256) ws[OFF_AUN + b*768 + i] = 0.f;
  #pragma unroll
  for (int g = 0; g < 3; ++g)
    __hip_atomic_store(&g2ct[(b*3 + g)*256 + n], 0.f, __ATOMIC_RELAXED, __HIP_MEMORY_SCOPE_AGENT);
}

extern "C" void kernel_launch(void* const* d_in, const int* in_sizes, int n_in,
                              void* d_out, int out_size, void* d_ws, size_t ws_size,
                              hipStream_t stream)
{
  const float* emb   = (const float*)d_in[0];
  const float* maskp = (const float*)d_in[1];
  const float* ctx   = (const float*)d_in[2];
  const float* cmask = (const float*)d_in[3];
  const float* inits = (const float*)d_in[4];
  const float* Ua    = (const float*)d_in[5];
  const float* Uab   = (const float*)d_in[6];
  const float* Wa    = (const float*)d_in[7];
  const float* Qw    = (const float*)d_in[8];
  const float* Uf    = (const float*)d_in[9];
  const float* Ufb   = (const float*)d_in[10];
  const float* va    = (const float*)d_in[11];
  const float* vab   = (const float*)d_in[12];
  const float* Wyz   = (const float*)d_in[13];
  const float* Wyzb  = (const float*)d_in[14];
  const float* Wyr   = (const float*)d_in[15];
  const float* Wyrb  = (const float*)d_in[16];
  const float* Wyh   = (const float*)d_in[17];
  const float* Wyhb  = (const float*)d_in[18];
  const float* Uhz   = (const float*)d_in[19];
  const float* Uhr   = (const float*)d_in[20];
  const float* Uhh   = (const float*)d_in[21];
  const float* Wcz   = (const float*)d_in[22];
  const float* Wcr   = (const float*)d_in[23];
  const float* Wch   = (const float*)d_in[24];
  const float* Uhz2  = (const float*)d_in[25];
  const float* Uhz2b = (const float*)d_in[26];
  const float* Uhr2  = (const float*)d_in[27];
  const float* Uhr2b = (const float*)d_in[28];
  const float* Uhh2  = (const float*)d_in[29];
  const float* Uhh2b = (const float*)d_in[30];
  float* out = (float*)d_out;
  float* ws  = (float*)d_ws;

  k_prep<<<dim3(6292), dim3(256), 0, stream>>>(Uhz, Uhr, Uhh, Uhz2, Uhr2, Uhh2,
                                               Wyz, Wyr, Wyh, Wa, Wcz, Wcr, Wch, Ua, ws);
  k_kcomb<<<dim3(128), dim3(256), 0, stream>>>(Uf, Qw, ws);
  k_embproj<<<dim3(48), dim3(256), 0, stream>>>(emb, Wyzb, Wyrb, Wyhb, ws);
  k_uactx<<<dim3(192), dim3(256), 0, stream>>>(ctx, ws);
  k_step0<<<dim3(16), dim3(256), 0, stream>>>(inits, maskp, Uab, Ufb, ws);

  for (int t = 0; t < 48; ++t) {
    k_cover<<<dim3(384), dim3(256), 0, stream>>>(va, ws);
    k_alpha<<<dim3(352), dim3(256), 0, stream>>>(t, ctx, cmask, vab, maskp,
                                                 Uab, Ufb, Uhz2b, Uhr2b, Uhh2b, out, ws);
  }
  (void)in_sizes; (void)n_in; (void)out_size; (void)ws_size;
}

// Round 7
// 6830.531 us; speedup vs baseline: 1.0832x; 1.0832x over previous
//
#include <hip/hip_runtime.h>
#include <hip/hip_bf16.h>
#include <stdint.h>

// Problem dims
#define T_  48
#define B_  16
#define HW_ 768
#define D_  684
#define N_  256
#define A_  512

// Workspace layout (float offsets).
#define OFF_SZ     0u
#define OFF_SR     196608u
#define OFF_SH     393216u
#define OFF_UHZT   589824u    // gates1 weights [k][n] x3 (196608)
#define OFF_UHZ2T  786432u    // gates2 h-weights [k][n] x3 (196608)
#define OFF_G2HP   983040u    // DOUBLE-BUF Uh2.h1 partials [2][b][8][3][256] = 196608 -> ends 1179648
                              //   (prep scratch for Wy transposes overlays here, consumed by embproj)
#define OFF_WAT    1179648u   // [k=256][a=512] (131072)
#define OFF_WCZT   1310720u   // [d=684][n=256] x3 (525312)
#define OFF_UAB    1836032u   // Ua bf16 [a=512][k=688] = 176128 floats -> 2012160
#define OFF_WAHP   2012160u   // Wa.h1 partials [b][8][512] = 65536 -> 2077696 (single buf, safe by ordering)
#define OFF_KCB    2186240u   // K_comb^T bf16 [a=512][k=128] = 32768 floats
#define OFF_G2CT   2219008u   // DOUBLE-BUF Wc.ct accum [2][b][3][256] = 24576 -> 2243584
#define OFF_CTR    2243584u   // 32 uints: ctrC[16], ctrA[16]
#define OFF_H1     2251776u   // DOUBLE-BUF h1 state [2][b][256] = 8192 -> 2259968
#define OFF_AP     2275008u   // alpha_past B*HW (12288)
#define OFF_AUN    2287296u   // per-step e sums (atomic) B*HW (12288)
#define OFF_UACTX  2299584u   // Ua_ctx bf16 [b][hw][a]; end 5445312

// d_out offsets
#define OUT_H2 0u
#define OUT_CT 196608u
#define OUT_AL 721920u
#define OUT_AP 1311744u

typedef __attribute__((ext_vector_type(8))) short bf16x8;
typedef __attribute__((ext_vector_type(16))) float floatx16;

__device__ __forceinline__ float sigf(float x)  { return 1.f / (1.f + __expf(-x)); }
__device__ __forceinline__ float tanhf_(float x){ float e = __expf(2.f*x); return 1.f - 2.f/(e + 1.f); }
__device__ __forceinline__ float bfval(unsigned short u){ return __uint_as_float(((unsigned)u) << 16); }
__device__ __forceinline__ unsigned short f2bf(float f){
  unsigned int x = __float_as_uint(f);
  return (unsigned short)((x + 0x7fffu + ((x >> 16) & 1u)) >> 16);  // RNE
}
__device__ __forceinline__ float aload(const float* p){
  return __hip_atomic_load(p, __ATOMIC_RELAXED, __HIP_MEMORY_SCOPE_AGENT);
}

// ---------------- prep: weight transposes + Ua->bf16 + zero alpha_past ----------------
__global__ void k_prep(const float* __restrict__ Uhz, const float* __restrict__ Uhr, const float* __restrict__ Uhh,
                       const float* __restrict__ Uhz2, const float* __restrict__ Uhr2, const float* __restrict__ Uhh2,
                       const float* __restrict__ Wyz, const float* __restrict__ Wyr, const float* __restrict__ Wyh,
                       const float* __restrict__ Wa, const float* __restrict__ Wcz, const float* __restrict__ Wcr,
                       const float* __restrict__ Wch, const float* __restrict__ Ua, float* __restrict__ ws)
{
  int i = blockIdx.x * 256 + threadIdx.x;
  if (i < 589824) {                     // 9 x (256x256) -> [k][n]
    int m = i >> 16, rem = i & 65535, r = rem >> 8, c = rem & 255;
    const float* s;
    unsigned dst;
    switch (m) { case 0: s=Uhz;  dst=OFF_UHZT;           break;
                 case 1: s=Uhr;  dst=OFF_UHZT+65536u;    break;
                 case 2: s=Uhh;  dst=OFF_UHZT+131072u;   break;
                 case 3: s=Uhz2; dst=OFF_UHZ2T;          break;
                 case 4: s=Uhr2; dst=OFF_UHZ2T+65536u;   break;
                 case 5: s=Uhh2; dst=OFF_UHZ2T+131072u;  break;
                 case 6: s=Wyz;  dst=983040u;            break;  // scratch (embproj)
                 case 7: s=Wyr;  dst=1048576u;           break;
                 default: s=Wyh; dst=1114112u;           break;}
    ws[dst + c*256 + r] = s[rem];
  } else if (i < 720896) {              // Wa [512][256] -> WaT [256][512]
    int j = i - 589824, r = j >> 8, c = j & 255;
    ws[OFF_WAT + c*512 + r] = Wa[j];
  } else if (i < 1246208) {             // Wc* [256][684] -> [684][256]
    int j = i - 720896; int m = j / 175104; int rem = j - m*175104;
    int r = rem / 684, c = rem - r*684;
    const float* s = (m == 0) ? Wcz : (m == 1) ? Wcr : Wch;
    ws[OFF_WCZT + m*175104 + c*256 + r] = s[rem];
  } else if (i < 1596416) {             // Ua [512][684] fp32 -> bf16 [a][688]
    int j = i - 1246208; int a = j / 684, d = j - a*684;
    unsigned short* uab = (unsigned short*)(ws + OFF_UAB);
    uab[(size_t)a*688 + d] = f2bf(Ua[j]);
  } else if (i < 1598464) {             // UaB k-padding zeros
    int j = i - 1596416; int a = j >> 2, d = 684 + (j & 3);
    unsigned short* uab = (unsigned short*)(ws + OFF_UAB);
    uab[(size_t)a*688 + d] = 0;
  } else if (i < 1610752) {             // zero alpha_past
    ws[OFF_AP + (i - 1598464)] = 0.f;
  }
}

// ---------------- K_comb bf16 [a=512][k=128]: one block per conv tap k ----------------
__global__ void __launch_bounds__(256) k_kcomb(const float* __restrict__ Uf, const float* __restrict__ Qw,
                                               float* __restrict__ ws)
{
  unsigned short* kcb = (unsigned short*)(ws + OFF_KCB);
  int tid = threadIdx.x, k = blockIdx.x;
  if (k >= 121) {
    for (int a = tid; a < 512; a += 256) kcb[(size_t)a*128 + k] = 0;
    return;
  }
  __shared__ float sQ[512];
  for (int c = tid; c < 512; c += 256) sQ[c] = Qw[c*121 + k];
  __syncthreads();
  int rl = tid >> 5, cl = tid & 31;
  for (int r0 = 0; r0 < 512; r0 += 8) {
    int a = r0 + rl;
    float acc = 0.f;
    #pragma unroll 4
    for (int c = cl; c < 512; c += 32) acc += Uf[(size_t)a*512 + c] * sQ[c];
    acc += __shfl_xor(acc, 1); acc += __shfl_xor(acc, 2); acc += __shfl_xor(acc, 4);
    acc += __shfl_xor(acc, 8); acc += __shfl_xor(acc, 16);
    if (cl == 0) kcb[(size_t)a*128 + k] = f2bf(acc);
  }
}

// ---------------- embedding projections (Wy* transposes from scratch) ----------------
__global__ void k_embproj(const float* __restrict__ emb, const float* __restrict__ bz,
                          const float* __restrict__ br, const float* __restrict__ bh,
                          float* __restrict__ ws)
{
  __shared__ __align__(16) float s_e[256 * 16];
  int tid = threadIdx.x, row0 = blockIdx.x * 16;
  for (int i = tid; i < 4096; i += 256) { int r = i >> 8, m = i & 255; s_e[m*16 + r] = emb[(row0 + r)*256 + m]; }
  __syncthreads();
  int n = tid;
  float az[16], arr[16], ahh[16];
  float vz = bz[n], vr = br[n], vh = bh[n];
  #pragma unroll
  for (int r = 0; r < 16; ++r) { az[r] = vz; arr[r] = vr; ahh[r] = vh; }
  for (int m = 0; m < 256; ++m) {
    float wz = ws[983040u + m*256 + n];
    float wr = ws[1048576u + m*256 + n];
    float wh = ws[1114112u + m*256 + n];
    #pragma unroll
    for (int r = 0; r < 16; ++r) { float e = s_e[m*16 + r]; az[r] += wz*e; arr[r] += wr*e; ahh[r] += wh*e; }
  }
  #pragma unroll
  for (int r = 0; r < 16; ++r) {
    int ro = (row0 + r)*256 + n;
    ws[OFF_SZ + ro] = az[r]; ws[OFF_SR + ro] = arr[r]; ws[OFF_SH + ro] = ahh[r];
  }
}

// ---------------- Ua_ctx via bf16 MFMA: grid 192 = b(16) x hw-chunk(12 of 64) ----------------
__global__ void __launch_bounds__(256) k_uactx(const float* __restrict__ ctx, float* __restrict__ ws)
{
  __shared__ unsigned short sA[64 * 24];
  int tid = threadIdx.x;
  int b = blockIdx.x / 12, ch = blockIdx.x % 12, hw0 = ch * 64;
  const unsigned short* uab = (const unsigned short*)(ws + OFF_UAB);
  int lane = tid & 63, w = tid >> 6, mw = w >> 1, nw = w & 1;
  int c5 = lane & 31, q = lane >> 5;
  int m = mw*32 + c5;
  int nb = nw*256;
  floatx16 acc[8];
  #pragma unroll
  for (int nt = 0; nt < 8; ++nt)
    #pragma unroll
    for (int r = 0; r < 16; ++r) acc[nt][r] = 0.f;
  int dd = tid >> 4, iw = tid & 15;
  for (int kt = 0; kt < 43; ++kt) {
    int d = kt*16 + dd;
    float4 v = {0.f, 0.f, 0.f, 0.f};
    if (d < 684) v = *(const float4*)(ctx + ((size_t)(b*684 + d))*768 + hw0 + iw*4);
    __syncthreads();
    sA[(iw*4 + 0)*24 + dd] = f2bf(v.x);
    sA[(iw*4 + 1)*24 + dd] = f2bf(v.y);
    sA[(iw*4 + 2)*24 + dd] = f2bf(v.z);
    sA[(iw*4 + 3)*24 + dd] = f2bf(v.w);
    __syncthreads();
    bf16x8 af = *(const bf16x8*)(sA + m*24 + q*8);
    #pragma unroll
    for (int nt = 0; nt < 8; ++nt) {
      bf16x8 bf = *(const bf16x8*)(uab + (size_t)(nb + nt*32 + c5)*688 + kt*16 + q*8);
      acc[nt] = __builtin_amdgcn_mfma_f32_32x32x16_bf16(af, bf, acc[nt], 0, 0, 0);
    }
  }
  unsigned short* up = (unsigned short*)(ws + OFF_UACTX);
  #pragma unroll
  for (int nt = 0; nt < 8; ++nt) {
    int col = nb + nt*32 + c5;
    #pragma unroll
    for (int r = 0; r < 16; ++r) {
      int row32 = (r & 3) + 8*(r >> 2) + 4*q;
      int hw = hw0 + mw*32 + row32;
      up[((size_t)(b*768 + hw))*512 + col] = f2bf(acc[nt][r]);
    }
  }
}

// ---------------- step0: h1(0), WAHP/G2HP copy0 partials, zero AUN/G2CT/ctr ----------------
__global__ void __launch_bounds__(256) k_step0(const float* __restrict__ inits, const float* __restrict__ maskp,
                                               float* __restrict__ ws)
{
  __shared__ float s_h[256], s_h1[256];
  int b = blockIdx.x, n = threadIdx.x;
  s_h[n] = inits[b*256 + n];
  __syncthreads();
  {
    float z = ws[OFF_SZ + b*256 + n], r = ws[OFF_SR + b*256 + n];
    float sh = ws[OFF_SH + b*256 + n], uh = 0.f;
    #pragma unroll 4
    for (int k = 0; k < 256; ++k) {
      float hk = s_h[k];
      z  += ws[OFF_UHZT + k*256 + n] * hk;
      r  += ws[OFF_UHZT + 65536u + k*256 + n] * hk;
      uh += ws[OFF_UHZT + 131072u + k*256 + n] * hk;
    }
    float z1 = sigf(z), r1 = sigf(r);
    float h1p = tanhf_(uh * r1 + sh);
    float m = maskp[b];
    float h = s_h[n];
    float h1 = m*(z1*h + (1.f - z1)*h1p) + (1.f - m)*h;
    s_h1[n] = h1;
    ws[OFF_H1 + b*256 + n] = h1;             // H1 copy0
  }
  __syncthreads();
  #pragma unroll
  for (int half = 0; half < 2; ++half) {
    int a = n + half*256;
    float acc = 0.f;
    #pragma unroll 4
    for (int k = 0; k < 256; ++k) acc += ws[OFF_WAT + k*512 + a] * s_h1[k];
    ws[OFF_WAHP + (size_t)(b*8 + 0)*512 + a] = acc;
    #pragma unroll
    for (int qq = 1; qq < 8; ++qq) ws[OFF_WAHP + (size_t)(b*8 + qq)*512 + a] = 0.f;
  }
  #pragma unroll
  for (int g = 0; g < 3; ++g) {
    float acc = 0.f;
    #pragma unroll 4
    for (int k = 0; k < 256; ++k) acc += ws[OFF_UHZ2T + g*65536u + k*256 + n] * s_h1[k];
    ws[OFF_G2HP + (size_t)((b*8 + 0)*3 + g)*256 + n] = acc;   // G2HP copy0
    #pragma unroll
    for (int qq = 1; qq < 8; ++qq) ws[OFF_G2HP + (size_t)((b*8 + qq)*3 + g)*256 + n] = 0.f;
  }
  for (int i = n; i < 768; i += 256) ws[OFF_AUN + b*768 + i] = 0.f;
  for (int g = 0; g < 3; ++g) ws[OFF_G2CT + (b*3 + g)*256 + n] = 0.f;   // copy0
  if (b == 0 && n < 32) ((unsigned*)(ws + OFF_CTR))[n] = 0u;
}

// ---------------- per-step fused kernel: cover | alpha | step-workers ----------------
struct SMemC { unsigned short sA[64*136]; float sWah[512]; float sVa[512]; };
struct SMemD { float s_al[768]; float s_red[4]; float s_ct[32]; };
struct SMemW { float s_h[256]; float s_part[3][8][32]; float s_h1[32]; };
union SMemU { SMemC c; SMemD d; SMemW w; };

__global__ void __launch_bounds__(256, 4) k_step(
    int t, const float* __restrict__ ctx, const float* __restrict__ cmask,
    const float* __restrict__ va, const float* __restrict__ vab,
    const float* __restrict__ maskp,
    const float* __restrict__ Uab, const float* __restrict__ Ufb,
    const float* __restrict__ bz2, const float* __restrict__ br2, const float* __restrict__ bh2,
    float* out, float* ws)
{
  __shared__ SMemU sm;
  const int tid = threadIdx.x;
  const int blk = blockIdx.x;
  unsigned* ctrC = (unsigned*)(ws + OFF_CTR);
  unsigned* ctrA = ctrC + 16;
  const unsigned cpy  = (unsigned)(t & 1);
  const unsigned cpyN = cpy ^ 1u;

  if (blk < 384) {
    // ======== COVER: MFMA conv GEMM + tanh + va partial e ========
    int b = blk / 24; int chA = blk % 24; int mt = chA >> 1; int nt2 = chA & 1;
    for (int i = tid; i < 512; i += 256) {
      float v = Uab[i] + Ufb[i];
      #pragma unroll
      for (int qq = 0; qq < 8; ++qq) v += ws[OFF_WAHP + (size_t)(b*8 + qq)*512 + i];
      sm.c.sWah[i] = v; sm.c.sVa[i] = va[i];
    }
    const float* ap = ws + OFF_AP + b*768;
    for (int idx = tid; idx < 64*128; idx += 256) {
      int r = idx & 63, k = idx >> 6;
      int hw = mt*64 + r; int hh = hw / 48; int wwp = hw - hh*48;
      float v = 0.f;
      if (k < 121) {
        int kh = k / 11, kw = k - kh*11;
        int shh = hh + kh - 5, sww = wwp + kw - 5;
        if (shh >= 0 && shh < 16 && sww >= 0 && sww < 48) v = ap[shh*48 + sww];
      }
      sm.c.sA[r*136 + k] = f2bf(v);
    }
    __syncthreads();
    int lane = tid & 63; int w = tid >> 6; int mw = w >> 1; int nw = w & 1;
    int c5 = lane & 31; int q = lane >> 5;
    bf16x8 af[8];
    {
      int m = mw*32 + c5;
      #pragma unroll
      for (int ks = 0; ks < 8; ++ks)
        af[ks] = *(const bf16x8*)(sm.c.sA + m*136 + ks*16 + q*8);
    }
    const unsigned short* kct = (const unsigned short*)(ws + OFF_KCB);
    const unsigned short* uact = (const unsigned short*)(ws + OFF_UACTX);
    float e_part[16];
    #pragma unroll
    for (int r = 0; r < 16; ++r) e_part[r] = 0.f;
    for (int sp = 0; sp < 2; ++sp) {
      int n_base = nt2*256 + nw*128 + sp*64;
      floatx16 acc[2];
      #pragma unroll
      for (int r = 0; r < 16; ++r) { acc[0][r] = 0.f; acc[1][r] = 0.f; }
      const bf16x8* kb0 = (const bf16x8*)(kct + (size_t)(n_base + c5)*128 + q*8);
      const bf16x8* kb1 = (const bf16x8*)(kct + (size_t)(n_base + 32 + c5)*128 + q*8);
      #pragma unroll
      for (int ks = 0; ks < 8; ++ks) {
        bf16x8 b0 = kb0[ks*2];
        bf16x8 b1 = kb1[ks*2];
        acc[0] = __builtin_amdgcn_mfma_f32_32x32x16_bf16(af[ks], b0, acc[0], 0, 0, 0);
        acc[1] = __builtin_amdgcn_mfma_f32_32x32x16_bf16(af[ks], b1, acc[1], 0, 0, 0);
      }
      #pragma unroll
      for (int half = 0; half < 2; ++half) {
        int col = n_base + half*32 + c5;
        float vav = sm.c.sVa[col], wah = sm.c.sWah[col];
        #pragma unroll
        for (int r = 0; r < 16; ++r) {
          int row32 = (r & 3) + 8*(r >> 2) + 4*q;
          int hw = mt*64 + mw*32 + row32;
          float x = acc[half][r] + wah + bfval(uact[((size_t)(b*768 + hw))*512 + col]);
          e_part[r] += vav * tanhf_(x);
        }
      }
    }
    #pragma unroll
    for (int r = 0; r < 16; ++r) {
      float v = e_part[r];
      v += __shfl_xor(v, 1); v += __shfl_xor(v, 2); v += __shfl_xor(v, 4);
      v += __shfl_xor(v, 8); v += __shfl_xor(v, 16);
      e_part[r] = v;
    }
    if (c5 == 0) {
      #pragma unroll
      for (int r = 0; r < 16; ++r) {
        int row32 = (r & 3) + 8*(r >> 2) + 4*q;
        int hw = mt*64 + mw*32 + row32;
        atomicAdd(&ws[OFF_AUN + b*768 + hw], e_part[r]);
      }
    }
    __syncthreads();   // drains vmcnt for all waves
    if (tid == 0)
      __hip_atomic_fetch_add(&ctrC[b], 1u, __ATOMIC_ACQ_REL, __HIP_MEMORY_SCOPE_AGENT);

  } else if (blk < 736) {
    // ======== ALPHA: wait cover(b) -> softmax + AP + ct + Wc.ct ========
    int ab = blk - 384;
    int b = ab / 22, dc = ab % 22;
    if (tid == 0) {
      unsigned target = 24u * (unsigned)(t + 1);
      while (__hip_atomic_load(&ctrC[b], __ATOMIC_RELAXED, __HIP_MEMORY_SCOPE_AGENT) < target)
        __builtin_amdgcn_s_sleep(8);
    }
    __syncthreads();
    float vb = vab[0];
    float local = 0.f;
    for (int i = tid; i < 768; i += 256) {
      float e = aload(&ws[OFF_AUN + b*768 + i]) + vb;
      float un = __expf(e) * cmask[b*768 + i];
      sm.d.s_al[i] = un; local += un;
    }
    local += __shfl_xor(local, 1); local += __shfl_xor(local, 2); local += __shfl_xor(local, 4);
    local += __shfl_xor(local, 8); local += __shfl_xor(local, 16); local += __shfl_xor(local, 32);
    if ((tid & 63) == 0) sm.d.s_red[tid >> 6] = local;
    __syncthreads();
    float inv = 1.f / (sm.d.s_red[0] + sm.d.s_red[1] + sm.d.s_red[2] + sm.d.s_red[3]);
    if (dc == 0) {
      float* outA = out + OUT_AL + (size_t)(t*16 + b)*768;
      float* outP = out + OUT_AP + (size_t)(t*16 + b)*768;
      for (int i = tid; i < 768; i += 256) {
        float av = sm.d.s_al[i] * inv;
        float np = ws[OFF_AP + b*768 + i] + av;
        ws[OFF_AP + b*768 + i] = np;
        outA[i] = av; outP[i] = np;
      }
    }
    {
      int dl = tid >> 3, qq = tid & 7;
      int d = dc*32 + dl;
      if (d < 684) {
        const float4* cp  = (const float4*)(ctx + ((size_t)(b*684 + d))*768);
        const float4* alp = (const float4*)sm.d.s_al;
        float s = 0.f;
        #pragma unroll 8
        for (int i = 0; i < 24; ++i) {
          float4 cv = cp[i*8 + qq]; float4 av = alp[i*8 + qq];
          s += cv.x*av.x + cv.y*av.y + cv.z*av.z + cv.w*av.w;
        }
        s += __shfl_xor(s, 1); s += __shfl_xor(s, 2); s += __shfl_xor(s, 4);
        s *= inv;
        if (qq == 0) {
          out[OUT_CT + (size_t)(t*16 + b)*684 + d] = s;
          sm.d.s_ct[dl] = s;
        }
      } else if (qq == 0) {
        sm.d.s_ct[dl] = 0.f;
      }
    }
    __syncthreads();
    {
      int d0 = dc*32;
      int jm = 684 - d0; if (jm > 32) jm = 32;
      #pragma unroll
      for (int g = 0; g < 3; ++g) {
        const float* Wb = ws + OFF_WCZT + g*175104u;
        float acc = 0.f;
        for (int j = 0; j < jm; ++j) acc += Wb[(d0 + j)*256 + tid] * sm.d.s_ct[j];
        atomicAdd(&ws[OFF_G2CT + cpy*12288u + (size_t)(b*3 + g)*256 + tid], acc);
      }
    }
    __syncthreads();   // drains vmcnt
    if (tid == 0)
      __hip_atomic_fetch_add(&ctrA[b], 1u, __ATOMIC_ACQ_REL, __HIP_MEMORY_SCOPE_AGENT);

  } else {
    // ======== WORKERS: wait alpha(b) -> h2 combine + next-step gates1/h1/partials ========
    int wid = blk - 736;
    int b = wid >> 3, q = wid & 7;
    if (tid == 0) {
      unsigned target = 22u * (unsigned)(t + 1);
      while (__hip_atomic_load(&ctrA[b], __ATOMIC_RELAXED, __HIP_MEMORY_SCOPE_AGENT) < target)
        __builtin_amdgcn_s_sleep(8);
    }
    __syncthreads();
    int n = tid;
    {
      float h1v = ws[OFF_H1 + cpy*4096u + b*256 + n];
      float gz = aload(&ws[OFF_G2CT + cpy*12288u + (b*3 + 0)*256 + n]);
      float gr = aload(&ws[OFF_G2CT + cpy*12288u + (b*3 + 1)*256 + n]);
      float gc = aload(&ws[OFF_G2CT + cpy*12288u + (b*3 + 2)*256 + n]);
      float gu = 0.f;
      #pragma unroll
      for (int qq = 0; qq < 8; ++qq) {
        gz += ws[OFF_G2HP + cpy*98304u + (size_t)((b*8 + qq)*3 + 0)*256 + n];
        gr += ws[OFF_G2HP + cpy*98304u + (size_t)((b*8 + qq)*3 + 1)*256 + n];
        gu += ws[OFF_G2HP + cpy*98304u + (size_t)((b*8 + qq)*3 + 2)*256 + n];
      }
      float z2 = sigf(gz + bz2[n]);
      float r2 = sigf(gr + br2[n]);
      float h2p = tanhf_(gc + (gu + bh2[n]) * r2);
      float h2 = z2*h1v + (1.f - z2)*h2p;
      float m = maskp[t*16 + b];
      float hv = m*h2 + (1.f - m)*h1v;
      if (q == 0) out[OUT_H2 + (size_t)(t*16 + b)*256 + n] = hv;
      sm.w.s_h[n] = hv;
    }
    if (q == 0) {
      for (int i = n; i < 768; i += 256) ws[OFF_AUN + b*768 + i] = 0.f;
      #pragma unroll
      for (int g = 0; g < 3; ++g) ws[OFF_G2CT + cpyN*12288u + (b*3 + g)*256 + n] = 0.f;
    }
    if (t >= 47) return;
    __syncthreads();
    {
      int nl = tid & 31, kq = tid >> 5;
      int col = q*32 + nl;
      const float* Wz = ws + OFF_UHZT;
      const float* Wr = ws + OFF_UHZT + 65536u;
      const float* Wh = ws + OFF_UHZT + 131072u;
      float a0 = 0.f, a1 = 0.f, a2 = 0.f;
      #pragma unroll 8
      for (int k = kq*32; k < kq*32 + 32; ++k) {
        float hk = sm.w.s_h[k];
        a0 += Wz[k*256 + col]*hk; a1 += Wr[k*256 + col]*hk; a2 += Wh[k*256 + col]*hk;
      }
      sm.w.s_part[0][kq][nl] = a0; sm.w.s_part[1][kq][nl] = a1; sm.w.s_part[2][kq][nl] = a2;
    }
    __syncthreads();
    if (tid < 32) {
      float g0 = 0.f, g1 = 0.f, g2 = 0.f;
      #pragma unroll
      for (int j = 0; j < 8; ++j) { g0 += sm.w.s_part[0][j][tid]; g1 += sm.w.s_part[1][j][tid]; g2 += sm.w.s_part[2][j][tid]; }
      int col = q*32 + tid;
      int ro = ((t+1)*16 + b)*256 + col;
      float z1 = sigf(g0 + ws[OFF_SZ + ro]);
      float r1 = sigf(g1 + ws[OFF_SR + ro]);
      float h1p = tanhf_(g2 * r1 + ws[OFF_SH + ro]);
      float m = maskp[(t+1)*16 + b];
      float h = sm.w.s_h[col];
      float h1 = m*(z1*h + (1.f - z1)*h1p) + (1.f - m)*h;
      sm.w.s_h1[tid] = h1;
      ws[OFF_H1 + cpyN*4096u + b*256 + col] = h1;
    }
    __syncthreads();
    {
      float acc0 = 0.f, acc1 = 0.f;
      #pragma unroll 8
      for (int j = 0; j < 32; ++j) {
        float h1j = sm.w.s_h1[j];
        acc0 += ws[OFF_WAT + (q*32 + j)*512 + tid]       * h1j;
        acc1 += ws[OFF_WAT + (q*32 + j)*512 + tid + 256] * h1j;
      }
      ws[OFF_WAHP + (size_t)(b*8 + q)*512 + tid]       = acc0;
      ws[OFF_WAHP + (size_t)(b*8 + q)*512 + tid + 256] = acc1;
    }
    #pragma unroll
    for (int g = 0; g < 3; ++g) {
      const float* Wb = ws + OFF_UHZ2T + g*65536u;
      float acc = 0.f;
      #pragma unroll 8
      for (int j = 0; j < 32; ++j) acc += Wb[(q*32 + j)*256 + tid] * sm.w.s_h1[j];
      ws[OFF_G2HP + cpyN*98304u + (size_t)((b*8 + q)*3 + g)*256 + tid] = acc;
    }
  }
}

extern "C" void kernel_launch(void* const* d_in, const int* in_sizes, int n_in,
                              void* d_out, int out_size, void* d_ws, size_t ws_size,
                              hipStream_t stream)
{
  const float* emb   = (const float*)d_in[0];
  const float* maskp = (const float*)d_in[1];
  const float* ctx   = (const float*)d_in[2];
  const float* cmask = (const float*)d_in[3];
  const float* inits = (const float*)d_in[4];
  const float* Ua    = (const float*)d_in[5];
  const float* Uab   = (const float*)d_in[6];
  const float* Wa    = (const float*)d_in[7];
  const float* Qw    = (const float*)d_in[8];
  const float* Uf    = (const float*)d_in[9];
  const float* Ufb   = (const float*)d_in[10];
  const float* va    = (const float*)d_in[11];
  const float* vab   = (const float*)d_in[12];
  const float* Wyz   = (const float*)d_in[13];
  const float* Wyzb  = (const float*)d_in[14];
  const float* Wyr   = (const float*)d_in[15];
  const float* Wyrb  = (const float*)d_in[16];
  const float* Wyh   = (const float*)d_in[17];
  const float* Wyhb  = (const float*)d_in[18];
  const float* Uhz   = (const float*)d_in[19];
  const float* Uhr   = (const float*)d_in[20];
  const float* Uhh   = (const float*)d_in[21];
  const float* Wcz   = (const float*)d_in[22];
  const float* Wcr   = (const float*)d_in[23];
  const float* Wch   = (const float*)d_in[24];
  const float* Uhz2  = (const float*)d_in[25];
  const float* Uhz2b = (const float*)d_in[26];
  const float* Uhr2  = (const float*)d_in[27];
  const float* Uhr2b = (const float*)d_in[28];
  const float* Uhh2  = (const float*)d_in[29];
  const float* Uhh2b = (const float*)d_in[30];
  float* out = (float*)d_out;
  float* ws  = (float*)d_ws;

  k_prep<<<dim3(6292), dim3(256), 0, stream>>>(Uhz, Uhr, Uhh, Uhz2, Uhr2, Uhh2,
                                               Wyz, Wyr, Wyh, Wa, Wcz, Wcr, Wch, Ua, ws);
  k_kcomb<<<dim3(128), dim3(256), 0, stream>>>(Uf, Qw, ws);
  k_embproj<<<dim3(48), dim3(256), 0, stream>>>(emb, Wyzb, Wyrb, Wyhb, ws);
  k_uactx<<<dim3(192), dim3(256), 0, stream>>>(ctx, ws);
  k_step0<<<dim3(16), dim3(256), 0, stream>>>(inits, maskp, ws);

  for (int t = 0; t < 48; ++t) {
    k_step<<<dim3(864), dim3(256), 0, stream>>>(t, ctx, cmask, va, vab, maskp,
                                                Uab, Ufb, Uhz2b, Uhr2b, Uhh2b, out, ws);
  }
  (void)in_sizes; (void)n_in; (void)out_size; (void)ws_size;
}

// Round 8
// 2713.680 us; speedup vs baseline: 2.7266x; 2.5171x over previous
//
#include <hip/hip_runtime.h>
#include <hip/hip_bf16.h>
#include <stdint.h>

// Problem dims
#define T_  48
#define B_  16
#define HW_ 768
#define D_  684
#define N_  256
#define A_  512

// Workspace layout (float offsets). Footprint <= proven 5445312 floats.
#define OFF_SZ     0u
#define OFF_SR     196608u
#define OFF_SH     393216u
#define OFF_UHZT   589824u    // gates1 weights [k][n] x3 (196608)
#define OFF_UHZ2T  786432u    // gates2 h-weights [k][n] x3 (196608)
#define OFF_G2HP   983040u    // DOUBLE-BUF Uh2.h1 partials [2][b][8][3][256] = 196608 -> 1179648
                              //   (prep scratch for Wy transposes overlays buf0; consumed by embproj before step0)
#define OFF_WAT    1179648u   // [k=256][a=512] (131072) -> 1310720
#define OFF_WCZT   1310720u   // [d=684][n=256] x3 (525312) -> 1836032
#define OFF_UAB    1836032u   // Ua bf16 [a=512][k=688] = 176128 -> 2012160
#define OFF_WAHP   2012160u   // Wa.h1 partials [b][8][512] = 65536 -> 2077696 (single buf: dispatch-ordered)
#define OFF_H1     2077696u   // DOUBLE-BUF h1 [2][b][256] = 8192 -> 2085888
#define OFF_KCB    2186240u   // K_comb^T bf16 [a=512][k=128] = 32768 -> 2219008
#define OFF_G2CT   2219008u   // DOUBLE-BUF Wc.ct accum [2][b][3][256] = 24576 -> 2243584
#define OFF_AP     2275008u   // alpha_past B*HW (12288)
#define OFF_AUN    2287296u   // per-step e sums (atomic) B*HW (12288)
#define OFF_UACTX  2299584u   // Ua_ctx bf16 [b][hw][a]; end 5445312

// d_out offsets
#define OUT_H2 0u
#define OUT_CT 196608u
#define OUT_AL 721920u
#define OUT_AP 1311744u

typedef __attribute__((ext_vector_type(8))) short bf16x8;
typedef __attribute__((ext_vector_type(16))) float floatx16;

__device__ __forceinline__ float sigf(float x)  { return 1.f / (1.f + __expf(-x)); }
__device__ __forceinline__ float tanhf_(float x){ float e = __expf(2.f*x); return 1.f - 2.f/(e + 1.f); }
__device__ __forceinline__ float bfval(unsigned short u){ return __uint_as_float(((unsigned)u) << 16); }
__device__ __forceinline__ unsigned short f2bf(float f){
  unsigned int x = __float_as_uint(f);
  return (unsigned short)((x + 0x7fffu + ((x >> 16) & 1u)) >> 16);  // RNE
}

// ---------------- prep: weight transposes + Ua->bf16 + zero alpha_past ----------------
__global__ void k_prep(const float* __restrict__ Uhz, const float* __restrict__ Uhr, const float* __restrict__ Uhh,
                       const float* __restrict__ Uhz2, const float* __restrict__ Uhr2, const float* __restrict__ Uhh2,
                       const float* __restrict__ Wyz, const float* __restrict__ Wyr, const float* __restrict__ Wyh,
                       const float* __restrict__ Wa, const float* __restrict__ Wcz, const float* __restrict__ Wcr,
                       const float* __restrict__ Wch, const float* __restrict__ Ua, float* __restrict__ ws)
{
  int i = blockIdx.x * 256 + threadIdx.x;
  if (i < 589824) {                     // 9 x (256x256) -> [k][n]
    int m = i >> 16, rem = i & 65535, r = rem >> 8, c = rem & 255;
    const float* s;
    unsigned dst;
    switch (m) { case 0: s=Uhz;  dst=OFF_UHZT;           break;
                 case 1: s=Uhr;  dst=OFF_UHZT+65536u;    break;
                 case 2: s=Uhh;  dst=OFF_UHZT+131072u;   break;
                 case 3: s=Uhz2; dst=OFF_UHZ2T;          break;
                 case 4: s=Uhr2; dst=OFF_UHZ2T+65536u;   break;
                 case 5: s=Uhh2; dst=OFF_UHZ2T+131072u;  break;
                 case 6: s=Wyz;  dst=983040u;            break;  // scratch (embproj)
                 case 7: s=Wyr;  dst=1048576u;           break;
                 default: s=Wyh; dst=1114112u;           break;}
    ws[dst + c*256 + r] = s[rem];
  } else if (i < 720896) {              // Wa [512][256] -> WaT [256][512]
    int j = i - 589824, r = j >> 8, c = j & 255;
    ws[OFF_WAT + c*512 + r] = Wa[j];
  } else if (i < 1246208) {             // Wc* [256][684] -> [684][256]
    int j = i - 720896; int m = j / 175104; int rem = j - m*175104;
    int r = rem / 684, c = rem - r*684;
    const float* s = (m == 0) ? Wcz : (m == 1) ? Wcr : Wch;
    ws[OFF_WCZT + m*175104 + c*256 + r] = s[rem];
  } else if (i < 1596416) {             // Ua [512][684] fp32 -> bf16 [a][688]
    int j = i - 1246208; int a = j / 684, d = j - a*684;
    unsigned short* uab = (unsigned short*)(ws + OFF_UAB);
    uab[(size_t)a*688 + d] = f2bf(Ua[j]);
  } else if (i < 1598464) {             // UaB k-padding zeros
    int j = i - 1596416; int a = j >> 2, d = 684 + (j & 3);
    unsigned short* uab = (unsigned short*)(ws + OFF_UAB);
    uab[(size_t)a*688 + d] = 0;
  } else if (i < 1610752) {             // zero alpha_past
    ws[OFF_AP + (i - 1598464)] = 0.f;
  }
}

// ---------------- K_comb bf16 [a=512][k=128]: one block per conv tap k ----------------
__global__ void __launch_bounds__(256) k_kcomb(const float* __restrict__ Uf, const float* __restrict__ Qw,
                                               float* __restrict__ ws)
{
  unsigned short* kcb = (unsigned short*)(ws + OFF_KCB);
  int tid = threadIdx.x, k = blockIdx.x;
  if (k >= 121) {
    for (int a = tid; a < 512; a += 256) kcb[(size_t)a*128 + k] = 0;
    return;
  }
  __shared__ float sQ[512];
  for (int c = tid; c < 512; c += 256) sQ[c] = Qw[c*121 + k];
  __syncthreads();
  int rl = tid >> 5, cl = tid & 31;
  for (int r0 = 0; r0 < 512; r0 += 8) {
    int a = r0 + rl;
    float acc = 0.f;
    #pragma unroll 4
    for (int c = cl; c < 512; c += 32) acc += Uf[(size_t)a*512 + c] * sQ[c];
    acc += __shfl_xor(acc, 1); acc += __shfl_xor(acc, 2); acc += __shfl_xor(acc, 4);
    acc += __shfl_xor(acc, 8); acc += __shfl_xor(acc, 16);
    if (cl == 0) kcb[(size_t)a*128 + k] = f2bf(acc);
  }
}

// ---------------- embedding projections (Wy* transposes from scratch) ----------------
__global__ void k_embproj(const float* __restrict__ emb, const float* __restrict__ bz,
                          const float* __restrict__ br, const float* __restrict__ bh,
                          float* __restrict__ ws)
{
  __shared__ __align__(16) float s_e[256 * 16];
  int tid = threadIdx.x, row0 = blockIdx.x * 16;
  for (int i = tid; i < 4096; i += 256) { int r = i >> 8, m = i & 255; s_e[m*16 + r] = emb[(row0 + r)*256 + m]; }
  __syncthreads();
  int n = tid;
  float az[16], arr[16], ahh[16];
  float vz = bz[n], vr = br[n], vh = bh[n];
  #pragma unroll
  for (int r = 0; r < 16; ++r) { az[r] = vz; arr[r] = vr; ahh[r] = vh; }
  for (int m = 0; m < 256; ++m) {
    float wz = ws[983040u + m*256 + n];
    float wr = ws[1048576u + m*256 + n];
    float wh = ws[1114112u + m*256 + n];
    #pragma unroll
    for (int r = 0; r < 16; ++r) { float e = s_e[m*16 + r]; az[r] += wz*e; arr[r] += wr*e; ahh[r] += wh*e; }
  }
  #pragma unroll
  for (int r = 0; r < 16; ++r) {
    int ro = (row0 + r)*256 + n;
    ws[OFF_SZ + ro] = az[r]; ws[OFF_SR + ro] = arr[r]; ws[OFF_SH + ro] = ahh[r];
  }
}

// ---------------- Ua_ctx via bf16 MFMA: grid 192 = b(16) x hw-chunk(12 of 64) ----------------
__global__ void __launch_bounds__(256) k_uactx(const float* __restrict__ ctx, float* __restrict__ ws)
{
  __shared__ unsigned short sA[64 * 24];
  int tid = threadIdx.x;
  int b = blockIdx.x / 12, ch = blockIdx.x % 12, hw0 = ch * 64;
  const unsigned short* uab = (const unsigned short*)(ws + OFF_UAB);
  int lane = tid & 63, w = tid >> 6, mw = w >> 1, nw = w & 1;
  int c5 = lane & 31, q = lane >> 5;
  int m = mw*32 + c5;
  int nb = nw*256;
  floatx16 acc[8];
  #pragma unroll
  for (int nt = 0; nt < 8; ++nt)
    #pragma unroll
    for (int r = 0; r < 16; ++r) acc[nt][r] = 0.f;
  int dd = tid >> 4, iw = tid & 15;
  for (int kt = 0; kt < 43; ++kt) {
    int d = kt*16 + dd;
    float4 v = {0.f, 0.f, 0.f, 0.f};
    if (d < 684) v = *(const float4*)(ctx + ((size_t)(b*684 + d))*768 + hw0 + iw*4);
    __syncthreads();
    sA[(iw*4 + 0)*24 + dd] = f2bf(v.x);
    sA[(iw*4 + 1)*24 + dd] = f2bf(v.y);
    sA[(iw*4 + 2)*24 + dd] = f2bf(v.z);
    sA[(iw*4 + 3)*24 + dd] = f2bf(v.w);
    __syncthreads();
    bf16x8 af = *(const bf16x8*)(sA + m*24 + q*8);
    #pragma unroll
    for (int nt = 0; nt < 8; ++nt) {
      bf16x8 bf = *(const bf16x8*)(uab + (size_t)(nb + nt*32 + c5)*688 + kt*16 + q*8);
      acc[nt] = __builtin_amdgcn_mfma_f32_32x32x16_bf16(af, bf, acc[nt], 0, 0, 0);
    }
  }
  unsigned short* up = (unsigned short*)(ws + OFF_UACTX);
  #pragma unroll
  for (int nt = 0; nt < 8; ++nt) {
    int col = nb + nt*32 + c5;
    #pragma unroll
    for (int r = 0; r < 16; ++r) {
      int row32 = (r & 3) + 8*(r >> 2) + 4*q;
      int hw = hw0 + mw*32 + row32;
      up[((size_t)(b*768 + hw))*512 + col] = f2bf(acc[nt][r]);
    }
  }
}

// ---------------- step0: h1(0) -> H1[0], WAHP/G2HP[0] partials, zero AUN/G2CT[0] ----------------
__global__ void __launch_bounds__(256) k_step0(const float* __restrict__ inits, const float* __restrict__ maskp,
                                               float* __restrict__ ws)
{
  __shared__ float s_h[256], s_h1[256];
  int b = blockIdx.x, n = threadIdx.x;
  s_h[n] = inits[b*256 + n];
  __syncthreads();
  {
    float z = ws[OFF_SZ + b*256 + n], r = ws[OFF_SR + b*256 + n];
    float sh = ws[OFF_SH + b*256 + n], uh = 0.f;
    #pragma unroll 4
    for (int k = 0; k < 256; ++k) {
      float hk = s_h[k];
      z  += ws[OFF_UHZT + k*256 + n] * hk;
      r  += ws[OFF_UHZT + 65536u + k*256 + n] * hk;
      uh += ws[OFF_UHZT + 131072u + k*256 + n] * hk;
    }
    float z1 = sigf(z), r1 = sigf(r);
    float h1p = tanhf_(uh * r1 + sh);
    float m = maskp[b];
    float h = s_h[n];
    float h1 = m*(z1*h + (1.f - z1)*h1p) + (1.f - m)*h;
    s_h1[n] = h1;
    ws[OFF_H1 + b*256 + n] = h1;             // buf 0
  }
  __syncthreads();
  #pragma unroll
  for (int half = 0; half < 2; ++half) {
    int a = n + half*256;
    float acc = 0.f;
    #pragma unroll 4
    for (int k = 0; k < 256; ++k) acc += ws[OFF_WAT + k*512 + a] * s_h1[k];
    ws[OFF_WAHP + (size_t)(b*8 + 0)*512 + a] = acc;
    #pragma unroll
    for (int qq = 1; qq < 8; ++qq) ws[OFF_WAHP + (size_t)(b*8 + qq)*512 + a] = 0.f;
  }
  #pragma unroll
  for (int g = 0; g < 3; ++g) {
    float acc = 0.f;
    #pragma unroll 4
    for (int k = 0; k < 256; ++k) acc += ws[OFF_UHZ2T + g*65536u + k*256 + n] * s_h1[k];
    ws[OFF_G2HP + (size_t)((b*8 + 0)*3 + g)*256 + n] = acc;   // buf 0
    #pragma unroll
    for (int qq = 1; qq < 8; ++qq) ws[OFF_G2HP + (size_t)((b*8 + qq)*3 + g)*256 + n] = 0.f;
  }
  for (int i = n; i < 768; i += 256) ws[OFF_AUN + b*768 + i] = 0.f;
  for (int g = 0; g < 3; ++g) ws[OFF_G2CT + (b*3 + g)*256 + n] = 0.f;   // buf 0
}

// ---------------- step1(t>=1): h2(t-1) combine + gates1(t) + h1(t) + partials ----------------
// grid 128 = b(16) x q(8); parity: read (t-1)&1, write t&1
__global__ void __launch_bounds__(256) k_step1(int t, const float* __restrict__ maskp,
                                               const float* __restrict__ bz2, const float* __restrict__ br2,
                                               const float* __restrict__ bh2,
                                               float* __restrict__ out, float* __restrict__ ws)
{
  __shared__ float s_h[256];
  __shared__ float s_part[3][8][32];
  __shared__ float s_h1[32];
  int tid = threadIdx.x;
  int b = blockIdx.x >> 3, q = blockIdx.x & 7;
  const unsigned pr = (unsigned)((t - 1) & 1);
  const unsigned pw = (unsigned)(t & 1);
  // ---- h2(t-1) combine (redundant per q) ----
  {
    int n = tid;
    float h1v = ws[OFF_H1 + pr*4096u + b*256 + n];
    float gz = ws[OFF_G2CT + pr*12288u + (b*3 + 0)*256 + n];
    float gr = ws[OFF_G2CT + pr*12288u + (b*3 + 1)*256 + n];
    float gc = ws[OFF_G2CT + pr*12288u + (b*3 + 2)*256 + n];
    float gu = 0.f;
    #pragma unroll
    for (int qq = 0; qq < 8; ++qq) {
      gz += ws[OFF_G2HP + pr*98304u + (size_t)((b*8 + qq)*3 + 0)*256 + n];
      gr += ws[OFF_G2HP + pr*98304u + (size_t)((b*8 + qq)*3 + 1)*256 + n];
      gu += ws[OFF_G2HP + pr*98304u + (size_t)((b*8 + qq)*3 + 2)*256 + n];
    }
    float z2 = sigf(gz + bz2[n]);
    float r2 = sigf(gr + br2[n]);
    float h2p = tanhf_(gc + (gu + bh2[n]) * r2);
    float h2 = z2*h1v + (1.f - z2)*h2p;
    float m = maskp[(t-1)*16 + b];
    float hv = m*h2 + (1.f - m)*h1v;
    if (q == 0) out[OUT_H2 + (size_t)((t-1)*16 + b)*256 + n] = hv;
    s_h[n] = hv;
  }
  if (q == 0) {
    for (int i = tid; i < 768; i += 256) ws[OFF_AUN + b*768 + i] = 0.f;
    #pragma unroll
    for (int g = 0; g < 3; ++g) ws[OFF_G2CT + pw*12288u + (b*3 + g)*256 + tid] = 0.f;
  }
  __syncthreads();
  // ---- gates1 for cols q*32..q*32+31 ----
  {
    int nl = tid & 31, kq = tid >> 5;
    int col = q*32 + nl;
    const float* Wz = ws + OFF_UHZT;
    const float* Wr = ws + OFF_UHZT + 65536u;
    const float* Wh = ws + OFF_UHZT + 131072u;
    float a0 = 0.f, a1 = 0.f, a2 = 0.f;
    #pragma unroll 8
    for (int k = kq*32; k < kq*32 + 32; ++k) {
      float hk = s_h[k];
      a0 += Wz[k*256 + col]*hk; a1 += Wr[k*256 + col]*hk; a2 += Wh[k*256 + col]*hk;
    }
    s_part[0][kq][nl] = a0; s_part[1][kq][nl] = a1; s_part[2][kq][nl] = a2;
  }
  __syncthreads();
  if (tid < 32) {
    float g0 = 0.f, g1 = 0.f, g2 = 0.f;
    #pragma unroll
    for (int j = 0; j < 8; ++j) { g0 += s_part[0][j][tid]; g1 += s_part[1][j][tid]; g2 += s_part[2][j][tid]; }
    int col = q*32 + tid;
    int ro = (t*16 + b)*256 + col;
    float z1 = sigf(g0 + ws[OFF_SZ + ro]);
    float r1 = sigf(g1 + ws[OFF_SR + ro]);
    float h1p = tanhf_(g2 * r1 + ws[OFF_SH + ro]);
    float m = maskp[t*16 + b];
    float h = s_h[col];
    float h1 = m*(z1*h + (1.f - z1)*h1p) + (1.f - m)*h;
    s_h1[tid] = h1;
    ws[OFF_H1 + pw*4096u + b*256 + col] = h1;
  }
  __syncthreads();
  // ---- WAHP over own 32 k's ----
  {
    float acc0 = 0.f, acc1 = 0.f;
    #pragma unroll 8
    for (int j = 0; j < 32; ++j) {
      float h1j = s_h1[j];
      acc0 += ws[OFF_WAT + (q*32 + j)*512 + tid]       * h1j;
      acc1 += ws[OFF_WAT + (q*32 + j)*512 + tid + 256] * h1j;
    }
    ws[OFF_WAHP + (size_t)(b*8 + q)*512 + tid]       = acc0;
    ws[OFF_WAHP + (size_t)(b*8 + q)*512 + tid + 256] = acc1;
  }
  // ---- G2HP[pw] (Uh2 . h1 partials) ----
  #pragma unroll
  for (int g = 0; g < 3; ++g) {
    const float* Wb = ws + OFF_UHZ2T + g*65536u;
    float acc = 0.f;
    #pragma unroll 8
    for (int j = 0; j < 32; ++j) acc += Wb[(q*32 + j)*256 + tid] * s_h1[j];
    ws[OFF_G2HP + pw*98304u + (size_t)((b*8 + q)*3 + g)*256 + tid] = acc;
  }
}

// ---------------- cover: bf16 MFMA GEMM + tanh + va partial e ----------------
// grid 384 = b(16) x mt(12) x nt2(2)
__global__ void __launch_bounds__(256) k_cover(const float* __restrict__ va,
                                               const float* __restrict__ Uab, const float* __restrict__ Ufb,
                                               float* __restrict__ ws)
{
  __shared__ unsigned short sA[64 * 136];
  __shared__ float sWah[512];
  __shared__ float sVa[512];
  int tid = threadIdx.x;
  int blk = blockIdx.x;
  int b = blk / 24; int chA = blk % 24; int mt = chA >> 1; int nt2 = chA & 1;
  for (int i = tid; i < 512; i += 256) {
    float v = Uab[i] + Ufb[i];
    #pragma unroll
    for (int qq = 0; qq < 8; ++qq) v += ws[OFF_WAHP + (size_t)(b*8 + qq)*512 + i];
    sWah[i] = v; sVa[i] = va[i];
  }
  const float* ap = ws + OFF_AP + b*768;
  for (int idx = tid; idx < 64*128; idx += 256) {
    int r = idx & 63, k = idx >> 6;
    int hw = mt*64 + r; int hh = hw / 48; int wwp = hw - hh*48;
    float v = 0.f;
    if (k < 121) {
      int kh = k / 11, kw = k - kh*11;
      int shh = hh + kh - 5, sww = wwp + kw - 5;
      if (shh >= 0 && shh < 16 && sww >= 0 && sww < 48) v = ap[shh*48 + sww];
    }
    sA[r*136 + k] = f2bf(v);
  }
  __syncthreads();
  int lane = tid & 63; int w = tid >> 6; int mw = w >> 1; int nw = w & 1;
  int c5 = lane & 31; int q = lane >> 5;
  bf16x8 af[8];
  {
    int m = mw*32 + c5;
    #pragma unroll
    for (int ks = 0; ks < 8; ++ks)
      af[ks] = *(const bf16x8*)(sA + m*136 + ks*16 + q*8);
  }
  const unsigned short* kct = (const unsigned short*)(ws + OFF_KCB);
  const unsigned short* uact = (const unsigned short*)(ws + OFF_UACTX);
  float e_part[16];
  #pragma unroll
  for (int r = 0; r < 16; ++r) e_part[r] = 0.f;
  for (int sp = 0; sp < 2; ++sp) {
    int n_base = nt2*256 + nw*128 + sp*64;
    floatx16 acc[2];
    #pragma unroll
    for (int r = 0; r < 16; ++r) { acc[0][r] = 0.f; acc[1][r] = 0.f; }
    const bf16x8* kb0 = (const bf16x8*)(kct + (size_t)(n_base + c5)*128 + q*8);
    const bf16x8* kb1 = (const bf16x8*)(kct + (size_t)(n_base + 32 + c5)*128 + q*8);
    #pragma unroll
    for (int ks = 0; ks < 8; ++ks) {
      bf16x8 b0 = kb0[ks*2];
      bf16x8 b1 = kb1[ks*2];
      acc[0] = __builtin_amdgcn_mfma_f32_32x32x16_bf16(af[ks], b0, acc[0], 0, 0, 0);
      acc[1] = __builtin_amdgcn_mfma_f32_32x32x16_bf16(af[ks], b1, acc[1], 0, 0, 0);
    }
    #pragma unroll
    for (int half = 0; half < 2; ++half) {
      int col = n_base + half*32 + c5;
      float vav = sVa[col], wah = sWah[col];
      #pragma unroll
      for (int r = 0; r < 16; ++r) {
        int row32 = (r & 3) + 8*(r >> 2) + 4*q;
        int hw = mt*64 + mw*32 + row32;
        float x = acc[half][r] + wah + bfval(uact[((size_t)(b*768 + hw))*512 + col]);
        e_part[r] += vav * tanhf_(x);
      }
    }
  }
  #pragma unroll
  for (int r = 0; r < 16; ++r) {
    float v = e_part[r];
    v += __shfl_xor(v, 1); v += __shfl_xor(v, 2); v += __shfl_xor(v, 4);
    v += __shfl_xor(v, 8); v += __shfl_xor(v, 16);
    e_part[r] = v;
  }
  if (c5 == 0) {
    #pragma unroll
    for (int r = 0; r < 16; ++r) {
      int row32 = (r & 3) + 8*(r >> 2) + 4*q;
      int hw = mt*64 + mw*32 + row32;
      atomicAdd(&ws[OFF_AUN + b*768 + hw], e_part[r]);
    }
  }
}

// ---------------- alpha: softmax + AP + outputs + ct + Wc.ct -> G2CT[t&1] ----------------
// grid 352 = b(16) x dc(22)
__global__ void __launch_bounds__(256) k_alpha(int t, const float* __restrict__ ctx, const float* __restrict__ cmask,
                                               const float* __restrict__ vab,
                                               float* __restrict__ out, float* __restrict__ ws)
{
  __shared__ __align__(16) float s_al[768];
  __shared__ float s_red[4];
  __shared__ float s_ct[32];
  int tid = threadIdx.x;
  int b = blockIdx.x / 22, dc = blockIdx.x % 22;
  const unsigned pw = (unsigned)(t & 1);
  float vb = vab[0];
  float local = 0.f;
  for (int i = tid; i < 768; i += 256) {
    float e = ws[OFF_AUN + b*768 + i] + vb;
    float un = __expf(e) * cmask[b*768 + i];
    s_al[i] = un; local += un;
  }
  local += __shfl_xor(local, 1); local += __shfl_xor(local, 2); local += __shfl_xor(local, 4);
  local += __shfl_xor(local, 8); local += __shfl_xor(local, 16); local += __shfl_xor(local, 32);
  if ((tid & 63) == 0) s_red[tid >> 6] = local;
  __syncthreads();
  float inv = 1.f / (s_red[0] + s_red[1] + s_red[2] + s_red[3]);
  if (dc == 0) {
    float* outA = out + OUT_AL + (size_t)(t*16 + b)*768;
    float* outP = out + OUT_AP + (size_t)(t*16 + b)*768;
    for (int i = tid; i < 768; i += 256) {
      float av = s_al[i] * inv;
      float np = ws[OFF_AP + b*768 + i] + av;
      ws[OFF_AP + b*768 + i] = np;
      outA[i] = av; outP[i] = np;
    }
  }
  {
    int dl = tid >> 3, qq = tid & 7;
    int d = dc*32 + dl;
    if (d < 684) {
      const float4* cp  = (const float4*)(ctx + ((size_t)(b*684 + d))*768);
      const float4* alp = (const float4*)s_al;
      float s = 0.f;
      #pragma unroll 8
      for (int i = 0; i < 24; ++i) {
        float4 cv = cp[i*8 + qq]; float4 av = alp[i*8 + qq];
        s += cv.x*av.x + cv.y*av.y + cv.z*av.z + cv.w*av.w;
      }
      s += __shfl_xor(s, 1); s += __shfl_xor(s, 2); s += __shfl_xor(s, 4);
      s *= inv;
      if (qq == 0) {
        out[OUT_CT + (size_t)(t*16 + b)*684 + d] = s;
        s_ct[dl] = s;
      }
    } else if (qq == 0) {
      s_ct[dl] = 0.f;
    }
  }
  __syncthreads();
  {
    int d0 = dc*32;
    int jm = 684 - d0; if (jm > 32) jm = 32;
    #pragma unroll
    for (int g = 0; g < 3; ++g) {
      const float* Wb = ws + OFF_WCZT + g*175104u;
      float acc = 0.f;
      for (int j = 0; j < jm; ++j) acc += Wb[(d0 + j)*256 + tid] * s_ct[j];
      atomicAdd(&ws[OFF_G2CT + pw*12288u + (size_t)(b*3 + g)*256 + tid], acc);
    }
  }
}

// ---------------- final combine for t=47 ----------------
__global__ void k_final(const float* __restrict__ maskp, const float* __restrict__ bz2,
                        const float* __restrict__ br2, const float* __restrict__ bh2,
                        float* __restrict__ out, float* __restrict__ ws)
{
  int b = blockIdx.x, n = threadIdx.x;
  const unsigned pr = 1u;  // 47 & 1
  float h1v = ws[OFF_H1 + pr*4096u + b*256 + n];
  float gz = ws[OFF_G2CT + pr*12288u + (b*3 + 0)*256 + n];
  float gr = ws[OFF_G2CT + pr*12288u + (b*3 + 1)*256 + n];
  float gc = ws[OFF_G2CT + pr*12288u + (b*3 + 2)*256 + n];
  float gu = 0.f;
  #pragma unroll
  for (int qq = 0; qq < 8; ++qq) {
    gz += ws[OFF_G2HP + pr*98304u + (size_t)((b*8 + qq)*3 + 0)*256 + n];
    gr += ws[OFF_G2HP + pr*98304u + (size_t)((b*8 + qq)*3 + 1)*256 + n];
    gu += ws[OFF_G2HP + pr*98304u + (size_t)((b*8 + qq)*3 + 2)*256 + n];
  }
  float z2 = sigf(gz + bz2[n]);
  float r2 = sigf(gr + br2[n]);
  float h2p = tanhf_(gc + (gu + bh2[n]) * r2);
  float h2 = z2*h1v + (1.f - z2)*h2p;
  float m = maskp[47*16 + b];
  out[OUT_H2 + (size_t)(47*16 + b)*256 + n] = m*h2 + (1.f - m)*h1v;
}

extern "C" void kernel_launch(void* const* d_in, const int* in_sizes, int n_in,
                              void* d_out, int out_size, void* d_ws, size_t ws_size,
                              hipStream_t stream)
{
  const float* emb   = (const float*)d_in[0];
  const float* maskp = (const float*)d_in[1];
  const float* ctx   = (const float*)d_in[2];
  const float* cmask = (const float*)d_in[3];
  const float* inits = (const float*)d_in[4];
  const float* Ua    = (const float*)d_in[5];
  const float* Uab   = (const float*)d_in[6];
  const float* Wa    = (const float*)d_in[7];
  const float* Qw    = (const float*)d_in[8];
  const float* Uf    = (const float*)d_in[9];
  const float* Ufb   = (const float*)d_in[10];
  const float* va    = (const float*)d_in[11];
  const float* vab   = (const float*)d_in[12];
  const float* Wyz   = (const float*)d_in[13];
  const float* Wyzb  = (const float*)d_in[14];
  const float* Wyr   = (const float*)d_in[15];
  const float* Wyrb  = (const float*)d_in[16];
  const float* Wyh   = (const float*)d_in[17];
  const float* Wyhb  = (const float*)d_in[18];
  const float* Uhz   = (const float*)d_in[19];
  const float* Uhr   = (const float*)d_in[20];
  const float* Uhh   = (const float*)d_in[21];
  const float* Wcz   = (const float*)d_in[22];
  const float* Wcr   = (const float*)d_in[23];
  const float* Wch   = (const float*)d_in[24];
  const float* Uhz2  = (const float*)d_in[25];
  const float* Uhz2b = (const float*)d_in[26];
  const float* Uhr2  = (const float*)d_in[27];
  const float* Uhr2b = (const float*)d_in[28];
  const float* Uhh2  = (const float*)d_in[29];
  const float* Uhh2b = (const float*)d_in[30];
  float* out = (float*)d_out;
  float* ws  = (float*)d_ws;

  k_prep<<<dim3(6292), dim3(256), 0, stream>>>(Uhz, Uhr, Uhh, Uhz2, Uhr2, Uhh2,
                                               Wyz, Wyr, Wyh, Wa, Wcz, Wcr, Wch, Ua, ws);
  k_kcomb<<<dim3(128), dim3(256), 0, stream>>>(Uf, Qw, ws);
  k_embproj<<<dim3(48), dim3(256), 0, stream>>>(emb, Wyzb, Wyrb, Wyhb, ws);
  k_uactx<<<dim3(192), dim3(256), 0, stream>>>(ctx, ws);
  k_step0<<<dim3(16), dim3(256), 0, stream>>>(inits, maskp, ws);

  k_cover<<<dim3(384), dim3(256), 0, stream>>>(va, Uab, Ufb, ws);
  k_alpha<<<dim3(352), dim3(256), 0, stream>>>(0, ctx, cmask, vab, out, ws);
  for (int t = 1; t < 48; ++t) {
    k_step1<<<dim3(128), dim3(256), 0, stream>>>(t, maskp, Uhz2b, Uhr2b, Uhh2b, out, ws);
    k_cover<<<dim3(384), dim3(256), 0, stream>>>(va, Uab, Ufb, ws);
    k_alpha<<<dim3(352), dim3(256), 0, stream>>>(t, ctx, cmask, vab, out, ws);
  }
  k_final<<<dim3(16), dim3(256), 0, stream>>>(maskp, Uhz2b, Uhr2b, Uhh2b, out, ws);
  (void)in_sizes; (void)n_in; (void)out_size; (void)ws_size;
}